// Round 2
// baseline (1287.848 us; speedup 1.0000x reference)
//
#include <hip/hip_runtime.h>
#include <hip/hip_bf16.h>
#include <stdint.h>

typedef __attribute__((ext_vector_type(8))) short short8_t;   // 8 x bf16 (4 VGPRs)
typedef __attribute__((ext_vector_type(4))) float f32x4;      // MFMA accum

__device__ __forceinline__ unsigned short f2bf(float f) {
  union { float f; unsigned int u; } a;
  a.f = f;
  unsigned int u = a.u;
  u += 0x7fffu + ((u >> 16) & 1u);   // round-to-nearest-even
  return (unsigned short)(u >> 16);
}

__device__ __forceinline__ void gload_lds16(const void* g, void* l) {
  __builtin_amdgcn_global_load_lds(
      (const __attribute__((address_space(1))) void*)g,
      (__attribute__((address_space(3))) void*)l, 16, 0, 0);
}

// ---------------- LayerNorm: fp32 -> bf16 normed rows ----------------
constexpr int D_IN = 4096;

__global__ __launch_bounds__(256) void ln_bf16_kernel(
    const float* __restrict__ x, const float* __restrict__ lnw,
    const float* __restrict__ lnb, unsigned short* __restrict__ out) {
  const int row = blockIdx.x;
  const int tid = threadIdx.x;
  const float* xr = x + (size_t)row * D_IN;

  float4 v[4];
  float sum = 0.f, sq = 0.f;
#pragma unroll
  for (int i = 0; i < 4; ++i) {
    v[i] = *reinterpret_cast<const float4*>(xr + i * 1024 + tid * 4);
    sum += v[i].x + v[i].y + v[i].z + v[i].w;
    sq += v[i].x * v[i].x + v[i].y * v[i].y + v[i].z * v[i].z + v[i].w * v[i].w;
  }
#pragma unroll
  for (int off = 32; off > 0; off >>= 1) {
    sum += __shfl_down(sum, off, 64);
    sq  += __shfl_down(sq, off, 64);
  }
  __shared__ float s_sum[4], s_sq[4];
  if ((tid & 63) == 0) { s_sum[tid >> 6] = sum; s_sq[tid >> 6] = sq; }
  __syncthreads();
  const float fs = s_sum[0] + s_sum[1] + s_sum[2] + s_sum[3];
  const float fq = s_sq[0] + s_sq[1] + s_sq[2] + s_sq[3];
  const float mean = fs * (1.f / D_IN);
  const float var = fq * (1.f / D_IN) - mean * mean;
  const float rstd = rsqrtf(var + 1e-5f);

  unsigned short* orow = out + (size_t)row * D_IN;
#pragma unroll
  for (int i = 0; i < 4; ++i) {
    const int col = i * 1024 + tid * 4;
    const float4 w = *reinterpret_cast<const float4*>(lnw + col);
    const float4 b = *reinterpret_cast<const float4*>(lnb + col);
    ushort4 o;
    o.x = f2bf((v[i].x - mean) * rstd * w.x + b.x);
    o.y = f2bf((v[i].y - mean) * rstd * w.y + b.y);
    o.z = f2bf((v[i].z - mean) * rstd * w.z + b.z);
    o.w = f2bf((v[i].w - mean) * rstd * w.w + b.w);
    *reinterpret_cast<ushort4*>(orow + col) = o;
  }
}

// ---------------- Weight cast fp32 -> bf16 ----------------
__global__ __launch_bounds__(256) void f32_to_bf16_kernel(
    const float* __restrict__ in, unsigned short* __restrict__ out) {
  const size_t i = ((size_t)blockIdx.x * 256 + threadIdx.x) * 8;
  const float4 a = *reinterpret_cast<const float4*>(in + i);
  const float4 b = *reinterpret_cast<const float4*>(in + i + 4);
  ushort4 lo, hi;
  lo.x = f2bf(a.x); lo.y = f2bf(a.y); lo.z = f2bf(a.z); lo.w = f2bf(a.w);
  hi.x = f2bf(b.x); hi.y = f2bf(b.y); hi.z = f2bf(b.z); hi.w = f2bf(b.w);
  *reinterpret_cast<ushort4*>(out + i) = lo;
  *reinterpret_cast<ushort4*>(out + i + 4) = hi;
}

// ---------------- 256x256 8-phase bf16 GEMM (m201 template, plain HIP) ------
// C = A(MxK) * B(NxK)^T + bias.  8 waves (2M x 4N), BK=64, 2 K-tiles/iter.
// LDS 128 KiB: A slot0/1 @ 0/32K, B slot0/1 @ 64K/96K; slot = 256 rows x 64
// bf16 (st_16x32-swizzled: byte ^= ((byte>>9)&1)<<5).
// Stage unit = 64 rows (8 KiB) = 1 global_load_lds_dwordx4 per thread; swizzle
// applied by pre-swizzling the per-lane GLOBAL source (LDS dest stays linear).

// swizzled LDS read of a 16B fragment
__device__ __forceinline__ short8_t lds_frag(const char* base, int row, int koff) {
  int d = row * 128 + koff;
  d ^= ((d >> 9) & 1) << 5;
  return *reinterpret_cast<const short8_t*>(base + d);
}

#define READ_A(SLOTA, MH)                                                      \
  _Pragma("unroll") for (int m_ = 0; m_ < 4; ++m_) {                           \
    _Pragma("unroll") for (int kk_ = 0; kk_ < 2; ++kk_)                        \
      af[m_][kk_] = lds_frag((SLOTA), wr128 + (MH)*64 + m_*16 + fr, kk_*64 + q16); \
  }

#define READ_B(SLOTB, NH)                                                      \
  _Pragma("unroll") for (int n_ = 0; n_ < 2; ++n_) {                           \
    _Pragma("unroll") for (int kk_ = 0; kk_ < 2; ++kk_)                        \
      bfr[(NH)*2+n_][kk_] = lds_frag((SLOTB), wc64 + ((NH)*2+n_)*16 + fr, kk_*64 + q16); \
  }

#define MFMA_Q(MH, NH)                                                         \
  _Pragma("unroll") for (int m_ = 0; m_ < 4; ++m_) {                           \
    _Pragma("unroll") for (int n_ = 0; n_ < 2; ++n_) {                         \
      _Pragma("unroll") for (int kk_ = 0; kk_ < 2; ++kk_)                      \
        acc[(MH)*4+m_][(NH)*2+n_] = __builtin_amdgcn_mfma_f32_16x16x32_bf16(   \
            af[m_][kk_], bfr[(NH)*2+n_][kk_], acc[(MH)*4+m_][(NH)*2+n_], 0, 0, 0); \
    }                                                                          \
  }

#define STAGE_A(S, U, KT) \
  gload_lds16(aSrc + (size_t)((U)*64) * K + (size_t)(KT)*64, ldsAw + (S)*32768 + (U)*8192)
#define STAGE_B(S, U, KT) \
  gload_lds16(bSrc + (size_t)((U)*64) * K + (size_t)(KT)*64, ldsBw + (S)*32768 + (U)*8192)

#define PH_MID                                         \
  __builtin_amdgcn_s_barrier();                        \
  asm volatile("s_waitcnt lgkmcnt(0)" ::: "memory");   \
  __builtin_amdgcn_s_setprio(1)
#define PH_END                                         \
  __builtin_amdgcn_s_setprio(0);                       \
  __builtin_amdgcn_s_barrier();                        \
  asm volatile("" ::: "memory")
#define PH_END_V(N)                                    \
  __builtin_amdgcn_s_setprio(0);                       \
  asm volatile("s_waitcnt vmcnt(" #N ")" ::: "memory");\
  __builtin_amdgcn_s_barrier();                        \
  asm volatile("" ::: "memory")

__global__ __launch_bounds__(512, 2) void gemm_8phase(
    const unsigned short* __restrict__ A,   // M x K bf16
    const unsigned short* __restrict__ B,   // N x K bf16
    const float* __restrict__ bias,         // N fp32
    float* __restrict__ C,                  // M x N fp32
    int M, int N, int K, int NXB, int q8) {
  extern __shared__ char smem[];
  const int tid = threadIdx.x;
  const int lane = tid & 63;
  const int wid = tid >> 6;
  const int wr = wid >> 2, wc = wid & 3;
  const int fr = lane & 15;
  const int q16 = (lane >> 4) * 16;
  const int wr128 = wr * 128;
  const int wc64 = wc * 64;

  // T1: bijective XCD swizzle (grid % 8 == 0)
  const int id = blockIdx.x;
  const int nid = (id & 7) * q8 + (id >> 3);
  const int by = nid / NXB, bx = nid - by * NXB;
  const int m0 = by * 256, n0 = bx * 256;

  // T2: pre-swizzled global source for linear global_load_lds dest
  const int s_lin = (tid * 16) ^ (tid & 32);   // byte ^= ((byte>>9)&1)<<5
  const int rsw = s_lin >> 7;                  // row within 64-row unit
  const int csw = (s_lin & 127) >> 1;          // k element within BK=64
  const unsigned short* aSrc = A + (size_t)(m0 + rsw) * K + csw;
  const unsigned short* bSrc = B + (size_t)(n0 + rsw) * K + csw;

  char* const ldsA0 = smem;
  char* const ldsA1 = smem + 32768;
  char* const ldsB0 = smem + 65536;
  char* const ldsB1 = smem + 98304;
  char* const ldsAw = smem + wid * 1024;           // wave-uniform stage bases
  char* const ldsBw = smem + 65536 + wid * 1024;

  f32x4 acc[8][4] = {};
  short8_t af[4][2], bfr[4][2];

  // ---- prologue: ktile0 -> slot0 (all 8 units), ktile1 -> slot1 (6 units) --
  STAGE_A(0,0,0); STAGE_A(0,1,0); STAGE_A(0,2,0); STAGE_A(0,3,0);
  STAGE_B(0,0,0); STAGE_B(0,1,0); STAGE_B(0,2,0); STAGE_B(0,3,0);
  STAGE_A(1,0,1); STAGE_A(1,1,1); STAGE_A(1,2,1); STAGE_A(1,3,1);
  STAGE_B(1,0,1); STAGE_B(1,1,1);
  asm volatile("s_waitcnt vmcnt(6)" ::: "memory");   // slot0 landed
  __builtin_amdgcn_s_barrier();
  asm volatile("" ::: "memory");

  const int NT = K >> 7;   // 2 K-tiles (2*64) per iteration
  for (int t = 0; t < NT - 1; ++t) {
    const int k1 = 2*t + 1, k2 = 2*t + 2, k3 = 2*t + 3;
    // P1: 12 ds_reads; stage current slot1 B-tail (read at P5/P6, lands by P4 vmcnt)
    READ_A(ldsA0, 0) READ_B(ldsB0, 0)
    STAGE_B(1,2,k1); STAGE_B(1,3,k1);
    asm volatile("s_waitcnt lgkmcnt(8)" ::: "memory");
    PH_MID; MFMA_Q(0,0) PH_END;
    // P2: stage slot0 A units 0,2 (freed by P1 reads)
    READ_B(ldsB0, 1)
    STAGE_A(0,0,k2); STAGE_A(0,2,k2);
    PH_MID; MFMA_Q(0,1) PH_END;
    // P3: stage slot0 B units 0,1 (freed by P2)
    READ_A(ldsA0, 1)
    STAGE_B(0,0,k2); STAGE_B(0,1,k2);
    PH_MID; MFMA_Q(1,0) PH_END;
    // P4: stage slot0 A units 1,3 (freed by P3); counted vmcnt -> slot1 landed
    STAGE_A(0,1,k2); STAGE_A(0,3,k2);
    PH_MID; MFMA_Q(1,1) PH_END_V(6);
    // P5: 12 ds_reads on slot1; stage slot0 B units 2,3
    READ_A(ldsA1, 0) READ_B(ldsB1, 0)
    STAGE_B(0,2,k2); STAGE_B(0,3,k2);
    asm volatile("s_waitcnt lgkmcnt(8)" ::: "memory");
    PH_MID; MFMA_Q(0,0) PH_END;
    // P6: stage slot1 A units 0,2 (freed by P5)
    READ_B(ldsB1, 1)
    STAGE_A(1,0,k3); STAGE_A(1,2,k3);
    PH_MID; MFMA_Q(0,1) PH_END;
    // P7: stage slot1 B units 0,1 (freed by P6)
    READ_A(ldsA1, 1)
    STAGE_B(1,0,k3); STAGE_B(1,1,k3);
    PH_MID; MFMA_Q(1,0) PH_END;
    // P8: stage slot1 A units 1,3 (freed by P7); counted vmcnt -> slot0 landed
    STAGE_A(1,1,k3); STAGE_A(1,3,k3);
    PH_MID; MFMA_Q(1,1) PH_END_V(6);
  }
  // ---- final iteration: only the slot1 B-tail stage remains ----
  {
    const int k1 = 2*NT - 1;
    READ_A(ldsA0, 0) READ_B(ldsB0, 0)
    STAGE_B(1,2,k1); STAGE_B(1,3,k1);
    PH_MID; MFMA_Q(0,0) PH_END;
    READ_B(ldsB0, 1)
    PH_MID; MFMA_Q(0,1) PH_END;
    READ_A(ldsA0, 1)
    PH_MID; MFMA_Q(1,0) PH_END;
    PH_MID; MFMA_Q(1,1) PH_END_V(0);
    READ_A(ldsA1, 0) READ_B(ldsB1, 0)
    PH_MID; MFMA_Q(0,0) PH_END;
    READ_B(ldsB1, 1)
    PH_MID; MFMA_Q(0,1) PH_END;
    READ_A(ldsA1, 1)
    PH_MID; MFMA_Q(1,0) PH_END;
    PH_MID; MFMA_Q(1,1)
    __builtin_amdgcn_s_setprio(0);
  }

  // ---- epilogue: C/D layout col = lane&15, row = (lane>>4)*4 + j ----
  const int cr = (lane >> 4) * 4;
#pragma unroll
  for (int ni = 0; ni < 4; ++ni) {
    const int col = n0 + wc64 + ni * 16 + fr;
    const float bv = bias[col];
#pragma unroll
    for (int mi = 0; mi < 8; ++mi) {
      const int row = m0 + wr128 + mi * 16 + cr;
      float* Cp = C + (size_t)row * N + col;
#pragma unroll
      for (int j = 0; j < 4; ++j)
        Cp[(size_t)j * N] = acc[mi][ni][j] + bv;
    }
  }
}

extern "C" void kernel_launch(void* const* d_in, const int* in_sizes, int n_in,
                              void* d_out, int out_size, void* d_ws, size_t ws_size,
                              hipStream_t stream) {
  const float* x    = (const float*)d_in[0];
  const float* w    = (const float*)d_in[1];
  const float* bias = (const float*)d_in[2];
  const float* lnw  = (const float*)d_in[3];
  const float* lnb  = (const float*)d_in[4];
  float* out = (float*)d_out;

  const int DIN  = 4096;
  const int M    = in_sizes[0] / DIN;      // 8192
  const int DOUT = in_sizes[2];            // 12288

  unsigned short* normA = (unsigned short*)d_ws;                 // M x DIN bf16
  unsigned short* wB    = normA + (size_t)M * DIN;               // DOUT x DIN bf16

  ln_bf16_kernel<<<M, 256, 0, stream>>>(x, lnw, lnb, normA);
  f32_to_bf16_kernel<<<((size_t)DOUT * DIN) / (256 * 8), 256, 0, stream>>>(w, wB);

  const int nwg = (M / 256) * (DOUT / 256);   // 1536, % 8 == 0
  (void)hipFuncSetAttribute((const void*)gemm_8phase,
                            hipFuncAttributeMaxDynamicSharedMemorySize, 131072);
  gemm_8phase<<<nwg, 512, 131072, stream>>>(normA, wB, bias, out,
                                            M, DOUT, DIN, DOUT / 256, nwg / 8);
}

// Round 3
// 1214.675 us; speedup vs baseline: 1.0602x; 1.0602x over previous
//
#include <hip/hip_runtime.h>
#include <hip/hip_bf16.h>
#include <stdint.h>

typedef __attribute__((ext_vector_type(8))) short short8_t;   // 8 x bf16 (4 VGPRs)
typedef __attribute__((ext_vector_type(4))) float f32x4;      // MFMA accum

__device__ __forceinline__ unsigned short f2bf(float f) {
  union { float f; unsigned int u; } a;
  a.f = f;
  unsigned int u = a.u;
  u += 0x7fffu + ((u >> 16) & 1u);   // round-to-nearest-even
  return (unsigned short)(u >> 16);
}

__device__ __forceinline__ void gload_lds16(const void* g, void* l) {
  __builtin_amdgcn_global_load_lds(
      (const __attribute__((address_space(1))) void*)g,
      (__attribute__((address_space(3))) void*)l, 16, 0, 0);
}

// ---------------- LayerNorm: fp32 -> bf16 normed rows ----------------
constexpr int D_IN = 4096;

__global__ __launch_bounds__(256) void ln_bf16_kernel(
    const float* __restrict__ x, const float* __restrict__ lnw,
    const float* __restrict__ lnb, unsigned short* __restrict__ out) {
  const int row = blockIdx.x;
  const int tid = threadIdx.x;
  const float* xr = x + (size_t)row * D_IN;

  float4 v[4];
  float sum = 0.f, sq = 0.f;
#pragma unroll
  for (int i = 0; i < 4; ++i) {
    v[i] = *reinterpret_cast<const float4*>(xr + i * 1024 + tid * 4);
    sum += v[i].x + v[i].y + v[i].z + v[i].w;
    sq += v[i].x * v[i].x + v[i].y * v[i].y + v[i].z * v[i].z + v[i].w * v[i].w;
  }
#pragma unroll
  for (int off = 32; off > 0; off >>= 1) {
    sum += __shfl_down(sum, off, 64);
    sq  += __shfl_down(sq, off, 64);
  }
  __shared__ float s_sum[4], s_sq[4];
  if ((tid & 63) == 0) { s_sum[tid >> 6] = sum; s_sq[tid >> 6] = sq; }
  __syncthreads();
  const float fs = s_sum[0] + s_sum[1] + s_sum[2] + s_sum[3];
  const float fq = s_sq[0] + s_sq[1] + s_sq[2] + s_sq[3];
  const float mean = fs * (1.f / D_IN);
  const float var = fq * (1.f / D_IN) - mean * mean;
  const float rstd = rsqrtf(var + 1e-5f);

  unsigned short* orow = out + (size_t)row * D_IN;
#pragma unroll
  for (int i = 0; i < 4; ++i) {
    const int col = i * 1024 + tid * 4;
    const float4 w = *reinterpret_cast<const float4*>(lnw + col);
    const float4 b = *reinterpret_cast<const float4*>(lnb + col);
    ushort4 o;
    o.x = f2bf((v[i].x - mean) * rstd * w.x + b.x);
    o.y = f2bf((v[i].y - mean) * rstd * w.y + b.y);
    o.z = f2bf((v[i].z - mean) * rstd * w.z + b.z);
    o.w = f2bf((v[i].w - mean) * rstd * w.w + b.w);
    *reinterpret_cast<ushort4*>(orow + col) = o;
  }
}

// ---------------- Weight cast fp32 -> bf16 ----------------
__global__ __launch_bounds__(256) void f32_to_bf16_kernel(
    const float* __restrict__ in, unsigned short* __restrict__ out) {
  const size_t i = ((size_t)blockIdx.x * 256 + threadIdx.x) * 8;
  const float4 a = *reinterpret_cast<const float4*>(in + i);
  const float4 b = *reinterpret_cast<const float4*>(in + i + 4);
  ushort4 lo, hi;
  lo.x = f2bf(a.x); lo.y = f2bf(a.y); lo.z = f2bf(a.z); lo.w = f2bf(a.w);
  hi.x = f2bf(b.x); hi.y = f2bf(b.y); hi.z = f2bf(b.z); hi.w = f2bf(b.w);
  *reinterpret_cast<ushort4*>(out + i) = lo;
  *reinterpret_cast<ushort4*>(out + i + 4) = hi;
}

// ---------------- 256x256 8-phase bf16 GEMM ------
// C = A(MxK) * B(NxK)^T + bias.  8 waves (2M x 4N), BK=64, 2 K-tiles/iter.
// LDS 128 KiB: A slot0/1 @ 0/32K, B slot0/1 @ 64K/96K; slot = 256 rows x 64
// bf16.  Swizzle: byte ^= ((row&7)<<4)  (3-bit XOR, G4) -> wave's 64 b128
// reads spread uniformly over all 8 16B slots (conflict-free).
// Stage: linear LDS dest (global_load_lds), INVERSE-swizzled global source.

__device__ __forceinline__ short8_t lds_frag(const char* base, int row, int koff) {
  int d = row * 128 + koff;
  d ^= ((d >> 7) & 7) << 4;   // == (row&7)<<4
  return *reinterpret_cast<const short8_t*>(base + d);
}

#define READ_A(SLOTA, MH)                                                      \
  _Pragma("unroll") for (int m_ = 0; m_ < 4; ++m_) {                           \
    _Pragma("unroll") for (int kk_ = 0; kk_ < 2; ++kk_)                        \
      af[m_][kk_] = lds_frag((SLOTA), wr128 + (MH)*64 + m_*16 + fr, kk_*64 + q16); \
  }

#define READ_B(SLOTB, NH)                                                      \
  _Pragma("unroll") for (int n_ = 0; n_ < 2; ++n_) {                           \
    _Pragma("unroll") for (int kk_ = 0; kk_ < 2; ++kk_)                        \
      bfr[(NH)*2+n_][kk_] = lds_frag((SLOTB), wc64 + ((NH)*2+n_)*16 + fr, kk_*64 + q16); \
  }

// kk outermost: dependent same-acc MFMA pairs are 8 apart, not back-to-back
#define MFMA_Q(MH, NH)                                                         \
  _Pragma("unroll") for (int kk_ = 0; kk_ < 2; ++kk_) {                        \
    _Pragma("unroll") for (int m_ = 0; m_ < 4; ++m_) {                         \
      _Pragma("unroll") for (int n_ = 0; n_ < 2; ++n_)                         \
        acc[(MH)*4+m_][(NH)*2+n_] = __builtin_amdgcn_mfma_f32_16x16x32_bf16(   \
            af[m_][kk_], bfr[(NH)*2+n_][kk_], acc[(MH)*4+m_][(NH)*2+n_], 0, 0, 0); \
    }                                                                          \
  }

#define STAGE_A(S, U, KT) \
  gload_lds16(aSrc + (size_t)((U)*64) * K + (size_t)(KT)*64, ldsAw + (S)*32768 + (U)*8192)
#define STAGE_B(S, U, KT) \
  gload_lds16(bSrc + (size_t)((U)*64) * K + (size_t)(KT)*64, ldsBw + (S)*32768 + (U)*8192)

#define PH_MID                                         \
  __builtin_amdgcn_s_barrier();                        \
  asm volatile("s_waitcnt lgkmcnt(0)" ::: "memory");   \
  __builtin_amdgcn_sched_barrier(0);                   \
  __builtin_amdgcn_s_setprio(1)
#define PH_END                                         \
  __builtin_amdgcn_sched_barrier(0);                   \
  __builtin_amdgcn_s_setprio(0);                       \
  __builtin_amdgcn_s_barrier();                        \
  asm volatile("" ::: "memory")
#define PH_END_V(N)                                    \
  __builtin_amdgcn_sched_barrier(0);                   \
  __builtin_amdgcn_s_setprio(0);                       \
  asm volatile("s_waitcnt vmcnt(" #N ")" ::: "memory");\
  __builtin_amdgcn_s_barrier();                        \
  asm volatile("" ::: "memory")

__global__ __launch_bounds__(512, 2) void gemm_8phase(
    const unsigned short* __restrict__ A,   // M x K bf16
    const unsigned short* __restrict__ B,   // N x K bf16
    const float* __restrict__ bias,         // N fp32
    float* __restrict__ C,                  // M x N fp32
    int M, int N, int K, int NXB, int q8) {
  extern __shared__ char smem[];
  const int tid = threadIdx.x;
  const int lane = tid & 63;
  const int wid = tid >> 6;
  const int wr = wid >> 2, wc = wid & 3;
  const int fr = lane & 15;
  const int q16 = (lane >> 4) * 16;
  const int wr128 = wr * 128;
  const int wc64 = wc * 64;

  // T1: bijective XCD swizzle (grid % 8 == 0)
  const int id = blockIdx.x;
  const int nid = (id & 7) * q8 + (id >> 3);
  const int by = nid / NXB, bx = nid - by * NXB;
  const int m0 = by * 256, n0 = bx * 256;

  // inverse-swizzled global source for linear global_load_lds dest
  const int s_log = (tid * 16) ^ (((tid >> 3) & 7) << 4);
  const int rsw = s_log >> 7;                  // row within 64-row unit
  const int csw = (s_log & 127) >> 1;          // k element within BK=64
  const unsigned short* aSrc = A + (size_t)(m0 + rsw) * K + csw;
  const unsigned short* bSrc = B + (size_t)(n0 + rsw) * K + csw;

  char* const ldsA0 = smem;
  char* const ldsA1 = smem + 32768;
  char* const ldsB0 = smem + 65536;
  char* const ldsB1 = smem + 98304;
  char* const ldsAw = smem + wid * 1024;           // wave-uniform stage bases
  char* const ldsBw = smem + 65536 + wid * 1024;

  f32x4 acc[8][4] = {};
  short8_t af[4][2], bfr[4][2];

  // ---- prologue: ktile0 -> slot0 (all 8 units), ktile1 -> slot1 (6 units) --
  STAGE_A(0,0,0); STAGE_A(0,1,0); STAGE_A(0,2,0); STAGE_A(0,3,0);
  STAGE_B(0,0,0); STAGE_B(0,1,0); STAGE_B(0,2,0); STAGE_B(0,3,0);
  STAGE_A(1,0,1); STAGE_A(1,1,1); STAGE_A(1,2,1); STAGE_A(1,3,1);
  STAGE_B(1,0,1); STAGE_B(1,1,1);
  asm volatile("s_waitcnt vmcnt(6)" ::: "memory");   // slot0 landed
  __builtin_amdgcn_s_barrier();
  asm volatile("" ::: "memory");

  const int NT = K >> 7;   // 2 K-tiles (2*64) per iteration
  for (int t = 0; t < NT - 1; ++t) {
    const int k1 = 2*t + 1, k2 = 2*t + 2, k3 = 2*t + 3;
    // P1: 12 ds_reads; stage current slot1 B-tail (read at P5/P6, lands by P4 vmcnt)
    READ_A(ldsA0, 0) READ_B(ldsB0, 0)
    STAGE_B(1,2,k1); STAGE_B(1,3,k1);
    asm volatile("s_waitcnt lgkmcnt(8)" ::: "memory");
    PH_MID; MFMA_Q(0,0) PH_END;
    // P2: stage slot0 A units 0,2 (freed by P1 reads)
    READ_B(ldsB0, 1)
    STAGE_A(0,0,k2); STAGE_A(0,2,k2);
    PH_MID; MFMA_Q(0,1) PH_END;
    // P3: stage slot0 B units 0,1 (freed by P2)
    READ_A(ldsA0, 1)
    STAGE_B(0,0,k2); STAGE_B(0,1,k2);
    PH_MID; MFMA_Q(1,0) PH_END;
    // P4: stage slot0 A units 1,3 (freed by P3); counted vmcnt -> slot1 landed
    STAGE_A(0,1,k2); STAGE_A(0,3,k2);
    PH_MID; MFMA_Q(1,1) PH_END_V(6);
    // P5: 12 ds_reads on slot1; stage slot0 B units 2,3
    READ_A(ldsA1, 0) READ_B(ldsB1, 0)
    STAGE_B(0,2,k2); STAGE_B(0,3,k2);
    asm volatile("s_waitcnt lgkmcnt(8)" ::: "memory");
    PH_MID; MFMA_Q(0,0) PH_END;
    // P6: stage slot1 A units 0,2 (freed by P5)
    READ_B(ldsB1, 1)
    STAGE_A(1,0,k3); STAGE_A(1,2,k3);
    PH_MID; MFMA_Q(0,1) PH_END;
    // P7: stage slot1 B units 0,1 (freed by P6)
    READ_A(ldsA1, 1)
    STAGE_B(1,0,k3); STAGE_B(1,1,k3);
    PH_MID; MFMA_Q(1,0) PH_END;
    // P8: stage slot1 A units 1,3 (freed by P7); counted vmcnt -> slot0 landed
    STAGE_A(1,1,k3); STAGE_A(1,3,k3);
    PH_MID; MFMA_Q(1,1) PH_END_V(6);
  }
  // ---- final iteration: only the slot1 B-tail stage remains ----
  {
    const int k1 = 2*NT - 1;
    READ_A(ldsA0, 0) READ_B(ldsB0, 0)
    STAGE_B(1,2,k1); STAGE_B(1,3,k1);
    PH_MID; MFMA_Q(0,0) PH_END;
    READ_B(ldsB0, 1)
    PH_MID; MFMA_Q(0,1) PH_END;
    READ_A(ldsA0, 1)
    PH_MID; MFMA_Q(1,0) PH_END;
    PH_MID; MFMA_Q(1,1) PH_END_V(0);
    READ_A(ldsA1, 0) READ_B(ldsB1, 0)
    PH_MID; MFMA_Q(0,0) PH_END;
    READ_B(ldsB1, 1)
    PH_MID; MFMA_Q(0,1) PH_END;
    READ_A(ldsA1, 1)
    PH_MID; MFMA_Q(1,0) PH_END;
    PH_MID; MFMA_Q(1,1)
    __builtin_amdgcn_sched_barrier(0);
    __builtin_amdgcn_s_setprio(0);
  }

  // ---- epilogue: C/D layout col = lane&15, row = (lane>>4)*4 + j ----
  // ni innermost: consecutive 64B segments complete 128B lines (clean writes)
  const int cr = (lane >> 4) * 4;
  float bv[4];
#pragma unroll
  for (int ni = 0; ni < 4; ++ni) bv[ni] = bias[n0 + wc64 + ni * 16 + fr];
#pragma unroll
  for (int mi = 0; mi < 8; ++mi) {
#pragma unroll
    for (int j = 0; j < 4; ++j) {
      const int row = m0 + wr128 + mi * 16 + cr + j;
      float* Cp = C + (size_t)row * N + n0 + wc64 + fr;
#pragma unroll
      for (int ni = 0; ni < 4; ++ni)
        Cp[ni * 16] = acc[mi][ni][j] + bv[ni];
    }
  }
}

extern "C" void kernel_launch(void* const* d_in, const int* in_sizes, int n_in,
                              void* d_out, int out_size, void* d_ws, size_t ws_size,
                              hipStream_t stream) {
  const float* x    = (const float*)d_in[0];
  const float* w    = (const float*)d_in[1];
  const float* bias = (const float*)d_in[2];
  const float* lnw  = (const float*)d_in[3];
  const float* lnb  = (const float*)d_in[4];
  float* out = (float*)d_out;

  const int DIN  = 4096;
  const int M    = in_sizes[0] / DIN;      // 8192
  const int DOUT = in_sizes[2];            // 12288

  unsigned short* normA = (unsigned short*)d_ws;                 // M x DIN bf16
  unsigned short* wB    = normA + (size_t)M * DIN;               // DOUT x DIN bf16

  ln_bf16_kernel<<<M, 256, 0, stream>>>(x, lnw, lnb, normA);
  f32_to_bf16_kernel<<<((size_t)DOUT * DIN) / (256 * 8), 256, 0, stream>>>(w, wB);

  const int nwg = (M / 256) * (DOUT / 256);   // 1536, % 8 == 0
  (void)hipFuncSetAttribute((const void*)gemm_8phase,
                            hipFuncAttributeMaxDynamicSharedMemorySize, 131072);
  gemm_8phase<<<nwg, 512, 131072, stream>>>(normA, wB, bias, out,
                                            M, DOUT, DIN, DOUT / 256, nwg / 8);
}

// Round 5
// 1069.140 us; speedup vs baseline: 1.2046x; 1.1361x over previous
//
#include <hip/hip_runtime.h>
#include <hip/hip_bf16.h>
#include <stdint.h>

typedef __attribute__((ext_vector_type(8))) short short8_t;   // 8 x bf16 (4 VGPRs)
typedef __attribute__((ext_vector_type(4))) float f32x4;      // MFMA accum / nt vec

__device__ __forceinline__ unsigned short f2bf(float f) {
  union { float f; unsigned int u; } a;
  a.f = f;
  unsigned int u = a.u;
  u += 0x7fffu + ((u >> 16) & 1u);   // round-to-nearest-even
  return (unsigned short)(u >> 16);
}

__device__ __forceinline__ void gload_lds16(const void* g, void* l) {
  __builtin_amdgcn_global_load_lds(
      (const __attribute__((address_space(1))) void*)g,
      (__attribute__((address_space(3))) void*)l, 16, 0, 0);
}

// ---------------- LayerNorm: fp32 -> bf16 normed rows ----------------
constexpr int D_IN = 4096;

__global__ __launch_bounds__(256) void ln_bf16_kernel(
    const float* __restrict__ x, const float* __restrict__ lnw,
    const float* __restrict__ lnb, unsigned short* __restrict__ out) {
  const int row = blockIdx.x;
  const int tid = threadIdx.x;
  const float* xr = x + (size_t)row * D_IN;

  f32x4 v[4];
  float sum = 0.f, sq = 0.f;
#pragma unroll
  for (int i = 0; i < 4; ++i) {
    // nt-load: x is read once; don't evict normA/wB from L3
    v[i] = __builtin_nontemporal_load(
        reinterpret_cast<const f32x4*>(xr + i * 1024 + tid * 4));
    sum += v[i][0] + v[i][1] + v[i][2] + v[i][3];
    sq += v[i][0]*v[i][0] + v[i][1]*v[i][1] + v[i][2]*v[i][2] + v[i][3]*v[i][3];
  }
#pragma unroll
  for (int off = 32; off > 0; off >>= 1) {
    sum += __shfl_down(sum, off, 64);
    sq  += __shfl_down(sq, off, 64);
  }
  __shared__ float s_sum[4], s_sq[4];
  if ((tid & 63) == 0) { s_sum[tid >> 6] = sum; s_sq[tid >> 6] = sq; }
  __syncthreads();
  const float fs = s_sum[0] + s_sum[1] + s_sum[2] + s_sum[3];
  const float fq = s_sq[0] + s_sq[1] + s_sq[2] + s_sq[3];
  const float mean = fs * (1.f / D_IN);
  const float var = fq * (1.f / D_IN) - mean * mean;
  const float rstd = rsqrtf(var + 1e-5f);

  unsigned short* orow = out + (size_t)row * D_IN;
#pragma unroll
  for (int i = 0; i < 4; ++i) {
    const int col = i * 1024 + tid * 4;
    const f32x4 w = *reinterpret_cast<const f32x4*>(lnw + col);
    const f32x4 b = *reinterpret_cast<const f32x4*>(lnb + col);
    ushort4 o;
    o.x = f2bf((v[i][0] - mean) * rstd * w[0] + b[0]);
    o.y = f2bf((v[i][1] - mean) * rstd * w[1] + b[1]);
    o.z = f2bf((v[i][2] - mean) * rstd * w[2] + b[2]);
    o.w = f2bf((v[i][3] - mean) * rstd * w[3] + b[3]);
    *reinterpret_cast<ushort4*>(orow + col) = o;
  }
}

// ---------------- Weight cast fp32 -> bf16 ----------------
__global__ __launch_bounds__(256) void f32_to_bf16_kernel(
    const float* __restrict__ in, unsigned short* __restrict__ out) {
  const size_t i = ((size_t)blockIdx.x * 256 + threadIdx.x) * 8;
  const f32x4 a = __builtin_nontemporal_load(reinterpret_cast<const f32x4*>(in + i));
  const f32x4 b = __builtin_nontemporal_load(reinterpret_cast<const f32x4*>(in + i + 4));
  ushort4 lo, hi;
  lo.x = f2bf(a[0]); lo.y = f2bf(a[1]); lo.z = f2bf(a[2]); lo.w = f2bf(a[3]);
  hi.x = f2bf(b[0]); hi.y = f2bf(b[1]); hi.z = f2bf(b[2]); hi.w = f2bf(b[3]);
  *reinterpret_cast<ushort4*>(out + i) = lo;
  *reinterpret_cast<ushort4*>(out + i + 4) = hi;
}

// ---------------- 256x256 8-phase bf16 GEMM ------
// C = A(MxK) * B(NxK)^T + bias.  8 waves (2M x 4N), BK=64, 2 K-tiles/iter.
// LDS 128 KiB K-loop: A slot0/1 @ 0/32K, B slot0/1 @ 64K/96K.
// Swizzle: byte ^= ((row&7)<<4) -> conflict-free b128 reads (verified: 0 conflicts).
// Stage: linear LDS dest (global_load_lds), inverse-swizzled global source.
// Epilogue: LDS-transposed, 1KB-contiguous nontemporal stores (no L2/L3 pollution).

__device__ __forceinline__ short8_t lds_frag(const char* base, int row, int koff) {
  int d = row * 128 + koff;
  d ^= ((d >> 7) & 7) << 4;   // == (row&7)<<4
  return *reinterpret_cast<const short8_t*>(base + d);
}

#define READ_A(SLOTA, MH)                                                      \
  _Pragma("unroll") for (int m_ = 0; m_ < 4; ++m_) {                           \
    _Pragma("unroll") for (int kk_ = 0; kk_ < 2; ++kk_)                        \
      af[m_][kk_] = lds_frag((SLOTA), wr128 + (MH)*64 + m_*16 + fr, kk_*64 + q16); \
  }

#define READ_B(SLOTB, NH)                                                      \
  _Pragma("unroll") for (int n_ = 0; n_ < 2; ++n_) {                           \
    _Pragma("unroll") for (int kk_ = 0; kk_ < 2; ++kk_)                        \
      bfr[(NH)*2+n_][kk_] = lds_frag((SLOTB), wc64 + ((NH)*2+n_)*16 + fr, kk_*64 + q16); \
  }

#define MFMA_Q(MH, NH)                                                         \
  _Pragma("unroll") for (int kk_ = 0; kk_ < 2; ++kk_) {                        \
    _Pragma("unroll") for (int m_ = 0; m_ < 4; ++m_) {                         \
      _Pragma("unroll") for (int n_ = 0; n_ < 2; ++n_)                         \
        acc[(MH)*4+m_][(NH)*2+n_] = __builtin_amdgcn_mfma_f32_16x16x32_bf16(   \
            af[m_][kk_], bfr[(NH)*2+n_][kk_], acc[(MH)*4+m_][(NH)*2+n_], 0, 0, 0); \
    }                                                                          \
  }

#define STAGE_A(S, U, KT) \
  gload_lds16(aSrc + (size_t)((U)*64) * K + (size_t)(KT)*64, ldsAw + (S)*32768 + (U)*8192)
#define STAGE_B(S, U, KT) \
  gload_lds16(bSrc + (size_t)((U)*64) * K + (size_t)(KT)*64, ldsBw + (S)*32768 + (U)*8192)

#define PH_MID                                         \
  __builtin_amdgcn_s_barrier();                        \
  asm volatile("s_waitcnt lgkmcnt(0)" ::: "memory");   \
  __builtin_amdgcn_s_setprio(1)
#define PH_END                                         \
  __builtin_amdgcn_s_setprio(0);                       \
  __builtin_amdgcn_s_barrier();                        \
  asm volatile("" ::: "memory")
#define PH_END_V(N)                                    \
  __builtin_amdgcn_s_setprio(0);                       \
  asm volatile("s_waitcnt vmcnt(" #N ")" ::: "memory");\
  __builtin_amdgcn_s_barrier();                        \
  asm volatile("" ::: "memory")

__global__ __launch_bounds__(512, 2) void gemm_8phase(
    const unsigned short* __restrict__ A,   // M x K bf16
    const unsigned short* __restrict__ B,   // N x K bf16
    const float* __restrict__ bias,         // N fp32
    float* __restrict__ C,                  // M x N fp32
    int M, int N, int K, int NYB, int BXP) {
  extern __shared__ char smem[];
  const int tid = threadIdx.x;
  const int lane = tid & 63;
  const int wid = tid >> 6;
  const int wr = wid >> 2, wc = wid & 3;
  const int fr = lane & 15;
  const int q16 = (lane >> 4) * 16;
  const int wr128 = wr * 128;
  const int wc64 = wc * 64;

  // T1 (B-reuse aimed): XCD x owns bx in [x*BXP, (x+1)*BXP); at any instant
  // the XCD's 32 CUs share ONE B panel (L2) and all XCDs share the A panels (L3).
  const int id = blockIdx.x;
  const int xcd = id & 7;
  const int slot = id >> 3;
  const int by = slot % NYB;
  const int bx = xcd * BXP + slot / NYB;
  const int m0 = by * 256, n0 = bx * 256;

  // inverse-swizzled global source for linear global_load_lds dest
  const int s_log = (tid * 16) ^ (((tid >> 3) & 7) << 4);
  const int rsw = s_log >> 7;                  // row within 64-row unit
  const int csw = (s_log & 127) >> 1;          // k element within BK=64
  const unsigned short* aSrc = A + (size_t)(m0 + rsw) * K + csw;
  const unsigned short* bSrc = B + (size_t)(n0 + rsw) * K + csw;

  char* const ldsA0 = smem;
  char* const ldsA1 = smem + 32768;
  char* const ldsB0 = smem + 65536;
  char* const ldsB1 = smem + 98304;
  char* const ldsAw = smem + wid * 1024;           // wave-uniform stage bases
  char* const ldsBw = smem + 65536 + wid * 1024;

  f32x4 acc[8][4] = {};
  short8_t af[4][2], bfr[4][2];

  // ---- prologue: ktile0 -> slot0 (all 8 units), ktile1 -> slot1 (6 units) --
  STAGE_A(0,0,0); STAGE_A(0,1,0); STAGE_A(0,2,0); STAGE_A(0,3,0);
  STAGE_B(0,0,0); STAGE_B(0,1,0); STAGE_B(0,2,0); STAGE_B(0,3,0);
  STAGE_A(1,0,1); STAGE_A(1,1,1); STAGE_A(1,2,1); STAGE_A(1,3,1);
  STAGE_B(1,0,1); STAGE_B(1,1,1);
  asm volatile("s_waitcnt vmcnt(6)" ::: "memory");   // slot0 landed
  __builtin_amdgcn_s_barrier();
  asm volatile("" ::: "memory");

  const int NT = K >> 7;   // 2 K-tiles (2*64) per iteration
  for (int t = 0; t < NT - 1; ++t) {
    const int k1 = 2*t + 1, k2 = 2*t + 2, k3 = 2*t + 3;
    // P1: 12 ds_reads; stage current slot1 B-tail (lands by P4 vmcnt)
    READ_A(ldsA0, 0) READ_B(ldsB0, 0)
    STAGE_B(1,2,k1); STAGE_B(1,3,k1);
    asm volatile("s_waitcnt lgkmcnt(8)" ::: "memory");
    PH_MID; MFMA_Q(0,0) PH_END;
    // P2: stage slot0 A units 0,2 (freed by P1 reads)
    READ_B(ldsB0, 1)
    STAGE_A(0,0,k2); STAGE_A(0,2,k2);
    PH_MID; MFMA_Q(0,1) PH_END;
    // P3: stage slot0 B units 0,1 (freed by P2)
    READ_A(ldsA0, 1)
    STAGE_B(0,0,k2); STAGE_B(0,1,k2);
    PH_MID; MFMA_Q(1,0) PH_END;
    // P4: stage slot0 A units 1,3 (freed by P3); counted vmcnt -> slot1 landed
    STAGE_A(0,1,k2); STAGE_A(0,3,k2);
    PH_MID; MFMA_Q(1,1) PH_END_V(6);
    // P5: 12 ds_reads on slot1; stage slot0 B units 2,3
    READ_A(ldsA1, 0) READ_B(ldsB1, 0)
    STAGE_B(0,2,k2); STAGE_B(0,3,k2);
    asm volatile("s_waitcnt lgkmcnt(8)" ::: "memory");
    PH_MID; MFMA_Q(0,0) PH_END;
    // P6: stage slot1 A units 0,2 (freed by P5)
    READ_B(ldsB1, 1)
    STAGE_A(1,0,k3); STAGE_A(1,2,k3);
    PH_MID; MFMA_Q(0,1) PH_END;
    // P7: stage slot1 B units 0,1 (freed by P6)
    READ_A(ldsA1, 1)
    STAGE_B(1,0,k3); STAGE_B(1,1,k3);
    PH_MID; MFMA_Q(1,0) PH_END;
    // P8: stage slot1 A units 1,3 (freed by P7); counted vmcnt -> slot0 landed
    STAGE_A(1,1,k3); STAGE_A(1,3,k3);
    PH_MID; MFMA_Q(1,1) PH_END_V(6);
  }
  // ---- final iteration: only the slot1 B-tail stage remains ----
  {
    const int k1 = 2*NT - 1;
    READ_A(ldsA0, 0) READ_B(ldsB0, 0)
    STAGE_B(1,2,k1); STAGE_B(1,3,k1);
    PH_MID; MFMA_Q(0,0) PH_END;
    READ_B(ldsB0, 1)
    PH_MID; MFMA_Q(0,1) PH_END;
    READ_A(ldsA0, 1)
    PH_MID; MFMA_Q(1,0) PH_END;
    PH_MID; MFMA_Q(1,1) PH_END_V(0);
    READ_A(ldsA1, 0) READ_B(ldsB1, 0)
    PH_MID; MFMA_Q(0,0) PH_END;
    READ_B(ldsB1, 1)
    PH_MID; MFMA_Q(0,1) PH_END;
    READ_A(ldsA1, 1)
    PH_MID; MFMA_Q(1,0) PH_END;
    PH_MID; MFMA_Q(1,1)
    __builtin_amdgcn_s_setprio(0);
  }

  // ---- epilogue: LDS-transpose -> fully-contiguous 1KB nt stores ----
  // buf layout: [2][64][260] fp32 (stride 260 => 16B-aligned rows, 4-bank skew)
  __syncthreads();   // all waves' K-loop LDS reads done before overwrite
  float* const buf0 = (float*)smem;
  float* const buf1 = (float*)smem + 64 * 260;
  const int cr = (lane >> 4) * 4;
  float bv[4];
#pragma unroll
  for (int ni = 0; ni < 4; ++ni) bv[ni] = bias[n0 + wc64 + ni * 16 + fr];

#pragma unroll
  for (int half = 0; half < 2; ++half) {
    // write: wr=0 waves -> buf0 (global rows m0+half*64+lr),
    //        wr=1 waves -> buf1 (global rows m0+128+half*64+lr)
    float* const wbuf = (wr == 0) ? buf0 : buf1;
#pragma unroll
    for (int mi4 = 0; mi4 < 4; ++mi4) {
      const int mi = half * 4 + mi4;
#pragma unroll
      for (int j = 0; j < 4; ++j) {
        const int lr = mi4 * 16 + cr + j;   // local row 0..63
#pragma unroll
        for (int ni = 0; ni < 4; ++ni)
          wbuf[lr * 260 + wc64 + ni * 16 + fr] = acc[mi][ni][j] + bv[ni];
      }
    }
    __syncthreads();
    // store: wave w handles rows idx = w*16..w*16+15 (idx<64: buf0, else buf1)
#pragma unroll
    for (int i = 0; i < 16; ++i) {
      const int idx = wid * 16 + i;   // 0..127, wave-uniform buffer choice
      const float* src = (idx < 64 ? buf0 + idx * 260 : buf1 + (idx - 64) * 260) + lane * 4;
      const int grow = m0 + (idx < 64 ? half * 64 + idx : 128 + half * 64 + (idx - 64));
      const f32x4 vv = *reinterpret_cast<const f32x4*>(src);
      __builtin_nontemporal_store(
          vv, reinterpret_cast<f32x4*>(C + (size_t)grow * N + n0) + lane);
    }
    __syncthreads();
  }
}

extern "C" void kernel_launch(void* const* d_in, const int* in_sizes, int n_in,
                              void* d_out, int out_size, void* d_ws, size_t ws_size,
                              hipStream_t stream) {
  const float* x    = (const float*)d_in[0];
  const float* w    = (const float*)d_in[1];
  const float* bias = (const float*)d_in[2];
  const float* lnw  = (const float*)d_in[3];
  const float* lnb  = (const float*)d_in[4];
  float* out = (float*)d_out;

  const int DIN  = 4096;
  const int M    = in_sizes[0] / DIN;      // 8192
  const int DOUT = in_sizes[2];            // 12288

  unsigned short* normA = (unsigned short*)d_ws;                 // M x DIN bf16
  unsigned short* wB    = normA + (size_t)M * DIN;               // DOUT x DIN bf16

  ln_bf16_kernel<<<M, 256, 0, stream>>>(x, lnw, lnb, normA);
  f32_to_bf16_kernel<<<((size_t)DOUT * DIN) / (256 * 8), 256, 0, stream>>>(w, wB);

  const int nwg = (M / 256) * (DOUT / 256);   // 1536
  const int smem_bytes = 2 * 64 * 260 * 4 > 131072 ? 2 * 64 * 260 * 4 : 131072; // 133120
  (void)hipFuncSetAttribute((const void*)gemm_8phase,
                            hipFuncAttributeMaxDynamicSharedMemorySize, 163840);
  gemm_8phase<<<nwg, 512, smem_bytes, stream>>>(normA, wB, bias, out,
                                                M, DOUT, DIN, M / 256, (DOUT / 256) / 8);
}

// Round 6
// 777.521 us; speedup vs baseline: 1.6564x; 1.3751x over previous
//
#include <hip/hip_runtime.h>
#include <hip/hip_bf16.h>
#include <stdint.h>

typedef __attribute__((ext_vector_type(8))) short short8_t;   // 8 x bf16 (4 VGPRs)
typedef __attribute__((ext_vector_type(4))) float f32x4;      // MFMA accum / nt vec

__device__ __forceinline__ unsigned short f2bf(float f) {
  union { float f; unsigned int u; } a;
  a.f = f;
  unsigned int u = a.u;
  u += 0x7fffu + ((u >> 16) & 1u);   // round-to-nearest-even
  return (unsigned short)(u >> 16);
}

__device__ __forceinline__ void gload_lds16(const void* g, void* l) {
  __builtin_amdgcn_global_load_lds(
      (const __attribute__((address_space(1))) void*)g,
      (__attribute__((address_space(3))) void*)l, 16, 0, 0);
}

// ---------------- LayerNorm: fp32 -> bf16 normed rows ----------------
constexpr int D_IN = 4096;

__global__ __launch_bounds__(256) void ln_bf16_kernel(
    const float* __restrict__ x, const float* __restrict__ lnw,
    const float* __restrict__ lnb, unsigned short* __restrict__ out) {
  const int row = blockIdx.x;
  const int tid = threadIdx.x;
  const float* xr = x + (size_t)row * D_IN;

  f32x4 v[4];
  float sum = 0.f, sq = 0.f;
#pragma unroll
  for (int i = 0; i < 4; ++i) {
    v[i] = __builtin_nontemporal_load(
        reinterpret_cast<const f32x4*>(xr + i * 1024 + tid * 4));
    sum += v[i][0] + v[i][1] + v[i][2] + v[i][3];
    sq += v[i][0]*v[i][0] + v[i][1]*v[i][1] + v[i][2]*v[i][2] + v[i][3]*v[i][3];
  }
#pragma unroll
  for (int off = 32; off > 0; off >>= 1) {
    sum += __shfl_down(sum, off, 64);
    sq  += __shfl_down(sq, off, 64);
  }
  __shared__ float s_sum[4], s_sq[4];
  if ((tid & 63) == 0) { s_sum[tid >> 6] = sum; s_sq[tid >> 6] = sq; }
  __syncthreads();
  const float fs = s_sum[0] + s_sum[1] + s_sum[2] + s_sum[3];
  const float fq = s_sq[0] + s_sq[1] + s_sq[2] + s_sq[3];
  const float mean = fs * (1.f / D_IN);
  const float var = fq * (1.f / D_IN) - mean * mean;
  const float rstd = rsqrtf(var + 1e-5f);

  unsigned short* orow = out + (size_t)row * D_IN;
#pragma unroll
  for (int i = 0; i < 4; ++i) {
    const int col = i * 1024 + tid * 4;
    const f32x4 w = *reinterpret_cast<const f32x4*>(lnw + col);
    const f32x4 b = *reinterpret_cast<const f32x4*>(lnb + col);
    ushort4 o;
    o.x = f2bf((v[i][0] - mean) * rstd * w[0] + b[0]);
    o.y = f2bf((v[i][1] - mean) * rstd * w[1] + b[1]);
    o.z = f2bf((v[i][2] - mean) * rstd * w[2] + b[2]);
    o.w = f2bf((v[i][3] - mean) * rstd * w[3] + b[3]);
    *reinterpret_cast<ushort4*>(orow + col) = o;
  }
}

// ---------------- Weight cast fp32 -> bf16 ----------------
__global__ __launch_bounds__(256) void f32_to_bf16_kernel(
    const float* __restrict__ in, unsigned short* __restrict__ out) {
  const size_t i = ((size_t)blockIdx.x * 256 + threadIdx.x) * 8;
  const f32x4 a = __builtin_nontemporal_load(reinterpret_cast<const f32x4*>(in + i));
  const f32x4 b = __builtin_nontemporal_load(reinterpret_cast<const f32x4*>(in + i + 4));
  ushort4 lo, hi;
  lo.x = f2bf(a[0]); lo.y = f2bf(a[1]); lo.z = f2bf(a[2]); lo.w = f2bf(a[3]);
  hi.x = f2bf(b[0]); hi.y = f2bf(b[1]); hi.z = f2bf(b[2]); hi.w = f2bf(b[3]);
  *reinterpret_cast<ushort4*>(out + i) = lo;
  *reinterpret_cast<ushort4*>(out + i + 4) = hi;
}

// ---------------- 256x256 8-phase bf16 GEMM ------
// C = A(MxK) * B(NxK)^T + bias.  8 waves (2M x 4N), BK=64, 2 K-tiles/iter.
// LDS 128 KiB K-loop: A slot0/1 @ 0/32K, B slot0/1 @ 64K/96K.
// Swizzle byte ^= ((row&7)<<4) -> conflict-free (verified 0 conflicts, r3/r5).
// Since row&7 == fr&7 for every fragment, the swizzled read address is
// laneBase(kk) + compile-time offset -> 4 base VGPRs + ds_read offset:imm,
// ZERO per-phase address VALU (r5 showed 284 VALU cyc/phase of recompute).
// Stage: linear LDS dest (global_load_lds), inverse-swizzled global source.
// Epilogue: LDS-transposed, 1KB-contiguous nontemporal stores.

#define RDA(S, KK, ROW) \
  (*reinterpret_cast<const short8_t*>(((KK) ? aB1 : aB0) + (S)*32768 + (ROW)*128))
#define RDB(S, KK, ROW) \
  (*reinterpret_cast<const short8_t*>(((KK) ? bB1 : bB0) + (S)*32768 + (ROW)*128))

#define READ_A(S, MH)                                          \
  _Pragma("unroll") for (int m_ = 0; m_ < 4; ++m_) {           \
    af[m_][0] = RDA(S, 0, (MH)*64 + m_*16);                    \
    af[m_][1] = RDA(S, 1, (MH)*64 + m_*16);                    \
  }

#define READ_B(S, NH)                                          \
  _Pragma("unroll") for (int n_ = 0; n_ < 2; ++n_) {           \
    bfr[(NH)*2+n_][0] = RDB(S, 0, ((NH)*2+n_)*16);             \
    bfr[(NH)*2+n_][1] = RDB(S, 1, ((NH)*2+n_)*16);             \
  }

#define MFMA_Q(MH, NH)                                                         \
  _Pragma("unroll") for (int kk_ = 0; kk_ < 2; ++kk_) {                        \
    _Pragma("unroll") for (int m_ = 0; m_ < 4; ++m_) {                         \
      _Pragma("unroll") for (int n_ = 0; n_ < 2; ++n_)                         \
        acc[(MH)*4+m_][(NH)*2+n_] = __builtin_amdgcn_mfma_f32_16x16x32_bf16(   \
            af[m_][kk_], bfr[(NH)*2+n_][kk_], acc[(MH)*4+m_][(NH)*2+n_], 0, 0, 0); \
    }                                                                          \
  }

#define STAGE_A(S, U, KT) \
  gload_lds16(aSrc + (size_t)((U)*64) * K + (size_t)(KT)*64, ldsAw + (S)*32768 + (U)*8192)
#define STAGE_B(S, U, KT) \
  gload_lds16(bSrc + (size_t)((U)*64) * K + (size_t)(KT)*64, ldsBw + (S)*32768 + (U)*8192)

#define PH_MID                                         \
  __builtin_amdgcn_s_barrier();                        \
  asm volatile("s_waitcnt lgkmcnt(0)" ::: "memory");   \
  __builtin_amdgcn_sched_barrier(0);                   \
  __builtin_amdgcn_s_setprio(1)
#define PH_END                                         \
  __builtin_amdgcn_sched_barrier(0);                   \
  __builtin_amdgcn_s_setprio(0);                       \
  __builtin_amdgcn_s_barrier();                        \
  asm volatile("" ::: "memory")
#define PH_END_V(N)                                    \
  __builtin_amdgcn_sched_barrier(0);                   \
  __builtin_amdgcn_s_setprio(0);                       \
  asm volatile("s_waitcnt vmcnt(" #N ")" ::: "memory");\
  __builtin_amdgcn_s_barrier();                        \
  asm volatile("" ::: "memory")

__global__ __launch_bounds__(512, 2) void gemm_8phase(
    const unsigned short* __restrict__ A,   // M x K bf16
    const unsigned short* __restrict__ B,   // N x K bf16
    const float* __restrict__ bias,         // N fp32
    float* __restrict__ C,                  // M x N fp32
    int M, int N, int K, int NYB, int BXP) {
  extern __shared__ char smem[];
  const int tid = threadIdx.x;
  const int lane = tid & 63;
  const int wid = tid >> 6;
  const int wr = wid >> 2, wc = wid & 3;
  const int fr = lane & 15;
  const int q16 = (lane >> 4) * 16;
  const int wr128 = wr * 128;
  const int wc64 = wc * 64;

  // T1 (B-reuse aimed): XCD x owns bx in [x*BXP, (x+1)*BXP).
  const int id = blockIdx.x;
  const int xcd = id & 7;
  const int slot = id >> 3;
  const int by = slot % NYB;
  const int bx = xcd * BXP + slot / NYB;
  const int m0 = by * 256, n0 = bx * 256;

  // inverse-swizzled global source for linear global_load_lds dest
  const int s_log = (tid * 16) ^ (((tid >> 3) & 7) << 4);
  const int rsw = s_log >> 7;                  // row within 64-row unit
  const int csw = (s_log & 127) >> 1;          // k element within BK=64
  const unsigned short* aSrc = A + (size_t)(m0 + rsw) * K + csw;
  const unsigned short* bSrc = B + (size_t)(n0 + rsw) * K + csw;

  char* const ldsAw = smem + wid * 1024;           // wave-uniform stage bases
  char* const ldsBw = smem + 65536 + wid * 1024;

  // 4 lane-base pointers: all fragment reads are base + compile-time offset
  const int s7 = (fr & 7) << 4;
  const char* const aB0 = smem + (wr128 + fr) * 128 + (q16 ^ s7);
  const char* const aB1 = smem + (wr128 + fr) * 128 + ((64 + q16) ^ s7);
  const char* const bB0 = smem + 65536 + (wc64 + fr) * 128 + (q16 ^ s7);
  const char* const bB1 = smem + 65536 + (wc64 + fr) * 128 + ((64 + q16) ^ s7);

  f32x4 acc[8][4] = {};
  short8_t af[4][2], bfr[4][2];

  // ---- prologue: ktile0 -> slot0 (all 8 units), ktile1 -> slot1 (6 units) --
  STAGE_A(0,0,0); STAGE_A(0,1,0); STAGE_A(0,2,0); STAGE_A(0,3,0);
  STAGE_B(0,0,0); STAGE_B(0,1,0); STAGE_B(0,2,0); STAGE_B(0,3,0);
  STAGE_A(1,0,1); STAGE_A(1,1,1); STAGE_A(1,2,1); STAGE_A(1,3,1);
  STAGE_B(1,0,1); STAGE_B(1,1,1);
  asm volatile("s_waitcnt vmcnt(6)" ::: "memory");   // slot0 landed
  __builtin_amdgcn_s_barrier();
  asm volatile("" ::: "memory");

  const int NT = K >> 7;   // 2 K-tiles (2*64) per iteration
  for (int t = 0; t < NT - 1; ++t) {
    const int k1 = 2*t + 1, k2 = 2*t + 2, k3 = 2*t + 3;
    // P1: 12 ds_reads; stage current slot1 B-tail (lands by P4 vmcnt)
    READ_A(0, 0) READ_B(0, 0)
    STAGE_B(1,2,k1); STAGE_B(1,3,k1);
    asm volatile("s_waitcnt lgkmcnt(8)" ::: "memory");
    PH_MID; MFMA_Q(0,0) PH_END;
    // P2: stage slot0 A units 0,2 (freed by P1 reads)
    READ_B(0, 1)
    STAGE_A(0,0,k2); STAGE_A(0,2,k2);
    PH_MID; MFMA_Q(0,1) PH_END;
    // P3: stage slot0 B units 0,1 (freed by P2)
    READ_A(0, 1)
    STAGE_B(0,0,k2); STAGE_B(0,1,k2);
    PH_MID; MFMA_Q(1,0) PH_END;
    // P4: stage slot0 A units 1,3 (freed by P3); counted vmcnt -> slot1 landed
    STAGE_A(0,1,k2); STAGE_A(0,3,k2);
    PH_MID; MFMA_Q(1,1) PH_END_V(6);
    // P5: 12 ds_reads on slot1; stage slot0 B units 2,3
    READ_A(1, 0) READ_B(1, 0)
    STAGE_B(0,2,k2); STAGE_B(0,3,k2);
    asm volatile("s_waitcnt lgkmcnt(8)" ::: "memory");
    PH_MID; MFMA_Q(0,0) PH_END;
    // P6: stage slot1 A units 0,2 (freed by P5)
    READ_B(1, 1)
    STAGE_A(1,0,k3); STAGE_A(1,2,k3);
    PH_MID; MFMA_Q(0,1) PH_END;
    // P7: stage slot1 B units 0,1 (freed by P6)
    READ_A(1, 1)
    STAGE_B(1,0,k3); STAGE_B(1,1,k3);
    PH_MID; MFMA_Q(1,0) PH_END;
    // P8: stage slot1 A units 1,3 (freed by P7); counted vmcnt -> slot0 landed
    STAGE_A(1,1,k3); STAGE_A(1,3,k3);
    PH_MID; MFMA_Q(1,1) PH_END_V(6);
  }
  // ---- final iteration: only the slot1 B-tail stage remains ----
  {
    const int k1 = 2*NT - 1;
    READ_A(0, 0) READ_B(0, 0)
    STAGE_B(1,2,k1); STAGE_B(1,3,k1);
    PH_MID; MFMA_Q(0,0) PH_END;
    READ_B(0, 1)
    PH_MID; MFMA_Q(0,1) PH_END;
    READ_A(0, 1)
    PH_MID; MFMA_Q(1,0) PH_END;
    PH_MID; MFMA_Q(1,1) PH_END_V(0);
    READ_A(1, 0) READ_B(1, 0)
    PH_MID; MFMA_Q(0,0) PH_END;
    READ_B(1, 1)
    PH_MID; MFMA_Q(0,1) PH_END;
    READ_A(1, 1)
    PH_MID; MFMA_Q(1,0) PH_END;
    PH_MID; MFMA_Q(1,1)
    __builtin_amdgcn_sched_barrier(0);
    __builtin_amdgcn_s_setprio(0);
  }

  // ---- epilogue: LDS-transpose -> fully-contiguous 1KB nt stores ----
  __syncthreads();   // all waves' K-loop LDS reads done before overwrite
  float* const buf0 = (float*)smem;
  float* const buf1 = (float*)smem + 64 * 260;
  const int cr = (lane >> 4) * 4;
  float bv[4];
#pragma unroll
  for (int ni = 0; ni < 4; ++ni) bv[ni] = bias[n0 + wc64 + ni * 16 + fr];

#pragma unroll
  for (int half = 0; half < 2; ++half) {
    float* const wbuf = (wr == 0) ? buf0 : buf1;
#pragma unroll
    for (int mi4 = 0; mi4 < 4; ++mi4) {
      const int mi = half * 4 + mi4;
#pragma unroll
      for (int j = 0; j < 4; ++j) {
        const int lr = mi4 * 16 + cr + j;   // local row 0..63
#pragma unroll
        for (int ni = 0; ni < 4; ++ni)
          wbuf[lr * 260 + wc64 + ni * 16 + fr] = acc[mi][ni][j] + bv[ni];
      }
    }
    __syncthreads();
#pragma unroll
    for (int i = 0; i < 16; ++i) {
      const int idx = wid * 16 + i;   // 0..127, wave-uniform buffer choice
      const float* src = (idx < 64 ? buf0 + idx * 260 : buf1 + (idx - 64) * 260) + lane * 4;
      const int grow = m0 + (idx < 64 ? half * 64 + idx : 128 + half * 64 + (idx - 64));
      const f32x4 vv = *reinterpret_cast<const f32x4*>(src);
      __builtin_nontemporal_store(
          vv, reinterpret_cast<f32x4*>(C + (size_t)grow * N + n0) + lane);
    }
    __syncthreads();
  }
}

extern "C" void kernel_launch(void* const* d_in, const int* in_sizes, int n_in,
                              void* d_out, int out_size, void* d_ws, size_t ws_size,
                              hipStream_t stream) {
  const float* x    = (const float*)d_in[0];
  const float* w    = (const float*)d_in[1];
  const float* bias = (const float*)d_in[2];
  const float* lnw  = (const float*)d_in[3];
  const float* lnb  = (const float*)d_in[4];
  float* out = (float*)d_out;

  const int DIN  = 4096;
  const int M    = in_sizes[0] / DIN;      // 8192
  const int DOUT = in_sizes[2];            // 12288

  unsigned short* normA = (unsigned short*)d_ws;                 // M x DIN bf16
  unsigned short* wB    = normA + (size_t)M * DIN;               // DOUT x DIN bf16

  ln_bf16_kernel<<<M, 256, 0, stream>>>(x, lnw, lnb, normA);
  f32_to_bf16_kernel<<<((size_t)DOUT * DIN) / (256 * 8), 256, 0, stream>>>(w, wB);

  const int nwg = (M / 256) * (DOUT / 256);   // 1536
  const int smem_bytes = 2 * 64 * 260 * 4 > 131072 ? 2 * 64 * 260 * 4 : 131072; // 133120
  (void)hipFuncSetAttribute((const void*)gemm_8phase,
                            hipFuncAttributeMaxDynamicSharedMemorySize, 163840);
  gemm_8phase<<<nwg, 512, smem_bytes, stream>>>(normA, wB, bias, out,
                                                M, DOUT, DIN, M / 256, (DOUT / 256) / 8);
}